// Round 13
// baseline (3538.598 us; speedup 1.0000x reference)
//
#include <hip/hip_runtime.h>
#include <hip/hip_bf16.h>

// Problem dims
#define B_    128
#define P_    196
#define ENCD  2048
#define LL    50
#define VV    10000
#define AA    512
#define DD    512
#define EE    512
#define TT    49
#define XKK   3072    // E + ENC + D
#define PROJN 2560    // A + ENC
#define VPAD  10048   // V rounded up to 64

// Output layout (float offsets)
#define OUT0_OFF 0
#define OUT1_OFF 62720000
#define OUT2_OFF 62726400
#define OUT3_OFF 62726528
#define OUT4_OFF 63955840

// Workspace layout (BYTE offsets)
#define WS_SI      0ull
#define WS_DLEN    512ull
#define WS_BATTN   1024ull        // 2560 f32
#define WS_BLSTM   11264ull       // 2048 f32
#define WS_MEANS   19456ull       // [128][2048] f32 (init only; head reused as gcnt)
#define WS_H       1068032ull     // [128][512] f32
#define WS_C       1330176ull
#define WS_HBF     1592320ull     // [128][512] bf16
#define WS_PROJ    1723392ull     // 4 slabs x [128][2560] f32
#define WS_XCAT    6966272ull     // [128][3072] bf16
#define WS_GATES   7752704ull     // 8 slabs x [128][2048] f32
#define WS_HSTORE  16141312ull    // [49*128][512] bf16
#define WS_WPROJ   22563840ull    // [2560][512] bf16
#define WS_WCAT    25185280ull    // [2048][3072] bf16 (gate-interleaved rows)
#define WS_FCW     37768192ull    // [10048][512] bf16
#define WS_WENC    48057344ull    // [512][2048] bf16
#define WS_EFEAT   50154496ull    // [25088][512] bf16
#define WS_ENCBF   75844608ull    // [128*196][2048] bf16
#define NEED_ENCBF 178605056ull

typedef __attribute__((ext_vector_type(4))) float f32x4;
typedef __attribute__((ext_vector_type(8))) short s16x8;

__device__ __forceinline__ float sigmoidf_(float x) { return 1.0f / (1.0f + __expf(-x)); }

__device__ __forceinline__ unsigned short f2bf(float x) {
    union { float f; unsigned int u; } v; v.f = x;
    unsigned int r = (v.u + 0x7FFFu + ((v.u >> 16) & 1u)) >> 16;
    return (unsigned short)r;
}
__device__ __forceinline__ float bf2f(unsigned short u) {
    return __uint_as_float(((unsigned int)u) << 16);
}

__device__ __forceinline__ void gload_lds16(const void* g, void* l) {
    __builtin_amdgcn_global_load_lds((const __attribute__((address_space(1))) void*)g,
                                     (__attribute__((address_space(3))) void*)l, 16, 0, 0);
}

// ---------------------------------------------------------------------------
// Stable descending argsort of cap_len (B=128), plus int-ish outputs
// ---------------------------------------------------------------------------
__global__ void sort_kernel(const int* __restrict__ cap_len, const int* __restrict__ enc_cap,
                            int* __restrict__ si, int* __restrict__ dlen,
                            float* __restrict__ out_caps, float* __restrict__ out_dlen,
                            float* __restrict__ out_sind)
{
    __shared__ int cl[B_];
    __shared__ int rank_to_idx[B_];
    int i = threadIdx.x;
    cl[i] = cap_len[i];
    __syncthreads();
    int my = cl[i];
    int r = 0;
    for (int j = 0; j < B_; ++j) {
        int oj = cl[j];
        if (oj > my || (oj == my && j < i)) ++r;
    }
    rank_to_idx[r] = i;
    __syncthreads();
    int src = rank_to_idx[i];
    si[i] = src;
    int dl = cl[src] - 1;
    dlen[i] = dl;
    out_dlen[i] = (float)dl;
    out_sind[i] = (float)src;
    for (int k = 0; k < LL; ++k) out_caps[i * LL + k] = (float)enc_cap[src * LL + k];
}

__global__ void bias_cat_kernel(const float* __restrict__ dec_b, const float* __restrict__ fbeta_b,
                                const float* __restrict__ bih, const float* __restrict__ bhh,
                                float* __restrict__ b_attn, float* __restrict__ b_lstm)
{
    int i = blockIdx.x * 256 + threadIdx.x;
    if (i < AA) b_attn[i] = dec_b[i];
    else if (i < PROJN) b_attn[i] = fbeta_b[i - AA];
    if (i < 2048) b_lstm[i] = bih[i] + bhh[i];
}

__global__ void enc_mean_sorted(const float* __restrict__ enc, const int* __restrict__ si,
                                float* __restrict__ means)
{
    int idx = blockIdx.x * 256 + threadIdx.x;   // B*ENC
    int b = idx >> 11, e = idx & 2047;
    const float* p = enc + (size_t)si[b] * P_ * ENCD + e;
    float s = 0.f;
    for (int q = 0; q < P_; ++q) s += p[(size_t)q * ENCD];
    means[idx] = s * (1.0f / 196.0f);
}

__global__ void zero_gcnt_kernel(unsigned int* gcnt)
{
    if (threadIdx.x < 32)
        __hip_atomic_store(&gcnt[threadIdx.x * 32], 0u, __ATOMIC_RELEASE, __HIP_MEMORY_SCOPE_AGENT);
}

// ---------------------------------------------------------------------------
// bf16 MFMA GEMM, double-buffered LDS, one barrier per k-iter, templated BK.
// BK2==64: XOR-swizzled LDS (swizzled SOURCE via linear gload dest + swizzled read).
// MODE 0: f32 out; MODE 1: bf16 out; MODE 2: fc epilogue (grid (T, N/64)).
// CONV: f32 sources (BK2 must be 32, no swizzle).
// ---------------------------------------------------------------------------
template<int MODE, bool CONV, int BK2>
__launch_bounds__(256)
__global__ void mfma_gemm(const void* __restrict__ Av, const void* __restrict__ Wv,
                          const float* __restrict__ bias, const int* __restrict__ dlen,
                          float* __restrict__ Cf, unsigned short* __restrict__ Cbf,
                          int K, int KC, long long ldc, long long slabStride, int Nreal)
{
    constexpr int RB = BK2 * 2;               // bytes per tile row
    constexpr int AL = (128 * RB) / 4096;     // A gload passes
    constexpr int WL = (64 * RB) / 4096;      // W gload passes
    constexpr bool SW = (BK2 == 64);          // swizzle enable
    __shared__ __align__(16) unsigned short As[2][128 * BK2];
    __shared__ __align__(16) unsigned short Ws[2][64 * BK2];
    const int tid  = threadIdx.x;
    const int wave = tid >> 6, lane = tid & 63;
    const int m0 = (MODE == 2 ? blockIdx.x : blockIdx.y) * 128;
    const int n0 = (MODE == 2 ? blockIdx.y : blockIdx.x) * 64;
    const int z  = blockIdx.z;
    const int kbeg = z * KC;
    const int nt = KC / BK2;
    const int r16 = lane & 15, kg = lane >> 4;
    const int swz = SW ? ((r16 & 7) << 3) : 0;   // shorts

    f32x4 acc[8];
    #pragma unroll
    for (int i = 0; i < 8; ++i) acc[i] = f32x4{0.f, 0.f, 0.f, 0.f};

    const int c_arow = tid >> 1, c_acb = (tid & 1) * 16;
    const int c_wrow = tid >> 2, c_wcb = (tid & 3) * 8;

    int buf = 0;

    if constexpr (!CONV) {
        const unsigned short* A = (const unsigned short*)Av;
        const unsigned short* W = (const unsigned short*)Wv;
        #pragma unroll
        for (int s = 0; s < AL; ++s) {
            int L = s * 4096 + wave * 1024 + lane * 16;
            int row = L / RB;
            int col = (L % RB) ^ (SW ? ((row & 7) << 4) : 0);
            gload_lds16(A + (size_t)(m0 + row) * K + kbeg + col / 2,
                        &As[0][(s * 4096 + wave * 1024) / 2]);
        }
        #pragma unroll
        for (int s = 0; s < WL; ++s) {
            int L = s * 4096 + wave * 1024 + lane * 16;
            int row = L / RB;
            int col = (L % RB) ^ (SW ? ((row & 7) << 4) : 0);
            gload_lds16(W + (size_t)(n0 + row) * K + kbeg + col / 2,
                        &Ws[0][(s * 4096 + wave * 1024) / 2]);
        }
        __syncthreads();
        for (int it = 0; it < nt; ++it) {
            if (it + 1 < nt) {
                int k1 = kbeg + (it + 1) * BK2;
                #pragma unroll
                for (int s = 0; s < AL; ++s) {
                    int L = s * 4096 + wave * 1024 + lane * 16;
                    int row = L / RB;
                    int col = (L % RB) ^ (SW ? ((row & 7) << 4) : 0);
                    gload_lds16(A + (size_t)(m0 + row) * K + k1 + col / 2,
                                &As[buf ^ 1][(s * 4096 + wave * 1024) / 2]);
                }
                #pragma unroll
                for (int s = 0; s < WL; ++s) {
                    int L = s * 4096 + wave * 1024 + lane * 16;
                    int row = L / RB;
                    int col = (L % RB) ^ (SW ? ((row & 7) << 4) : 0);
                    gload_lds16(W + (size_t)(n0 + row) * K + k1 + col / 2,
                                &Ws[buf ^ 1][(s * 4096 + wave * 1024) / 2]);
                }
            }
            #pragma unroll
            for (int kk2 = 0; kk2 < BK2 / 32; ++kk2) {
                s16x8 bfrag = *(const s16x8*)&Ws[buf][(wave * 16 + r16) * BK2 + ((kk2 * 32 + kg * 8) ^ swz)];
                #pragma unroll
                for (int i = 0; i < 8; ++i) {
                    s16x8 afrag = *(const s16x8*)&As[buf][(i * 16 + r16) * BK2 + ((kk2 * 32 + kg * 8) ^ swz)];
                    acc[i] = __builtin_amdgcn_mfma_f32_16x16x32_bf16(afrag, bfrag, acc[i], 0, 0, 0);
                }
            }
            __syncthreads();
            buf ^= 1;
        }
    } else {
        static_assert(!CONV || BK2 == 32, "CONV path requires BK2==32");
        const float* A = (const float*)Av;
        const float* W = (const float*)Wv;
        float ra[16], rw[8];
        #pragma unroll
        for (int j = 0; j < 16; ++j) ra[j] = A[(size_t)(m0 + c_arow) * K + kbeg + c_acb + j];
        #pragma unroll
        for (int j = 0; j < 8; ++j)  rw[j] = W[(size_t)(n0 + c_wrow) * K + kbeg + c_wcb + j];
        {
            unsigned short t0[16], t1[8];
            #pragma unroll
            for (int j = 0; j < 16; ++j) t0[j] = f2bf(ra[j]);
            #pragma unroll
            for (int j = 0; j < 8; ++j)  t1[j] = f2bf(rw[j]);
            *(s16x8*)&As[0][c_arow * 32 + c_acb]     = *(s16x8*)&t0[0];
            *(s16x8*)&As[0][c_arow * 32 + c_acb + 8] = *(s16x8*)&t0[8];
            *(s16x8*)&Ws[0][c_wrow * 32 + c_wcb]     = *(s16x8*)&t1[0];
        }
        __syncthreads();
        for (int it = 0; it < nt; ++it) {
            float ra2[16], rw2[8];
            bool more = (it + 1 < nt);
            if (more) {
                int k1 = kbeg + (it + 1) * 32;
                #pragma unroll
                for (int j = 0; j < 16; ++j) ra2[j] = A[(size_t)(m0 + c_arow) * K + k1 + c_acb + j];
                #pragma unroll
                for (int j = 0; j < 8; ++j)  rw2[j] = W[(size_t)(n0 + c_wrow) * K + k1 + c_wcb + j];
            }
            s16x8 bfrag = *(const s16x8*)&Ws[buf][(wave * 16 + r16) * 32 + kg * 8];
            #pragma unroll
            for (int i = 0; i < 8; ++i) {
                s16x8 afrag = *(const s16x8*)&As[buf][(i * 16 + r16) * 32 + kg * 8];
                acc[i] = __builtin_amdgcn_mfma_f32_16x16x32_bf16(afrag, bfrag, acc[i], 0, 0, 0);
            }
            if (more) {
                unsigned short t0[16], t1[8];
                #pragma unroll
                for (int j = 0; j < 16; ++j) t0[j] = f2bf(ra2[j]);
                #pragma unroll
                for (int j = 0; j < 8; ++j)  t1[j] = f2bf(rw2[j]);
                *(s16x8*)&As[buf ^ 1][c_arow * 32 + c_acb]     = *(s16x8*)&t0[0];
                *(s16x8*)&As[buf ^ 1][c_arow * 32 + c_acb + 8] = *(s16x8*)&t0[8];
                *(s16x8*)&Ws[buf ^ 1][c_wrow * 32 + c_wcb]     = *(s16x8*)&t1[0];
            }
            __syncthreads();
            buf ^= 1;
        }
    }

    int n = n0 + wave * 16 + r16;
    float bv = 0.f;
    if (bias && z == 0) bv = (MODE == 2) ? (n < Nreal ? bias[n] : 0.f) : bias[n];
    float* Cz = Cf + (size_t)z * slabStride;
    #pragma unroll
    for (int i = 0; i < 8; ++i) {
        #pragma unroll
        for (int r = 0; r < 4; ++r) {
            int m = m0 + i * 16 + kg * 4 + r;
            float v = acc[i][r] + bv;
            if (MODE == 0) {
                Cz[(size_t)m * ldc + n] = v;
            } else if (MODE == 1) {
                Cbf[(size_t)m * ldc + n] = f2bf(v);
            } else {
                int bb = m & 127, tt2 = m >> 7;
                if (n < Nreal)
                    Cf[((size_t)bb * TT + tt2) * VV + n] = (dlen[bb] > tt2) ? v : 0.f;
            }
        }
    }
}

// ---------------------------------------------------------------------------
// gates GEMM (split-K x8, BK=64 swizzled, gate-interleaved wcat rows) with
// fine-grained fused LSTM pointwise: grid (32, 1, 8); ntile's 64 cols are
// 16 d-quadruples (d in [16*ntile,16*ntile+16)). Last of the 8 z-blocks per
// ntile (completion counter) sums slabs (contiguous float4) and updates h,c.
// ---------------------------------------------------------------------------
__launch_bounds__(256)
__global__ void gates_pw2_kernel(const unsigned short* __restrict__ Axc,
                                 const unsigned short* __restrict__ Wc,
                                 float* __restrict__ gates, const float* __restrict__ blstm,
                                 const int* __restrict__ dlen,
                                 float* __restrict__ h, float* __restrict__ c,
                                 unsigned short* __restrict__ h_bf,
                                 unsigned short* __restrict__ hstore,
                                 unsigned int* __restrict__ gcnt, int t)
{
    constexpr int BK2 = 64, RB = 128, AL = 4, WL = 2, NT = 6;   // KC = 384
    __shared__ __align__(16) unsigned short As[2][128 * BK2];
    __shared__ __align__(16) unsigned short Ws[2][64 * BK2];
    __shared__ int slast;
    const int tid  = threadIdx.x;
    const int wave = tid >> 6, lane = tid & 63;
    const int ntile = blockIdx.x;
    const int z  = blockIdx.z;
    const int n0 = ntile * 64;
    const int kbeg = z * 384;
    const int r16 = lane & 15, kg = lane >> 4;
    const int swz = (r16 & 7) << 3;

    f32x4 acc[8];
    #pragma unroll
    for (int i = 0; i < 8; ++i) acc[i] = f32x4{0.f, 0.f, 0.f, 0.f};

    int buf = 0;
    #pragma unroll
    for (int s = 0; s < AL; ++s) {
        int L = s * 4096 + wave * 1024 + lane * 16;
        int row = L / RB;
        int col = (L % RB) ^ ((row & 7) << 4);
        gload_lds16(Axc + (size_t)row * XKK + kbeg + col / 2,
                    &As[0][(s * 4096 + wave * 1024) / 2]);
    }
    #pragma unroll
    for (int s = 0; s < WL; ++s) {
        int L = s * 4096 + wave * 1024 + lane * 16;
        int row = L / RB;
        int col = (L % RB) ^ ((row & 7) << 4);
        gload_lds16(Wc + (size_t)(n0 + row) * XKK + kbeg + col / 2,
                    &Ws[0][(s * 4096 + wave * 1024) / 2]);
    }
    __syncthreads();
    for (int it = 0; it < NT; ++it) {
        if (it + 1 < NT) {
            int k1 = kbeg + (it + 1) * BK2;
            #pragma unroll
            for (int s = 0; s < AL; ++s) {
                int L = s * 4096 + wave * 1024 + lane * 16;
                int row = L / RB;
                int col = (L % RB) ^ ((row & 7) << 4);
                gload_lds16(Axc + (size_t)row * XKK + k1 + col / 2,
                            &As[buf ^ 1][(s * 4096 + wave * 1024) / 2]);
            }
            #pragma unroll
            for (int s = 0; s < WL; ++s) {
                int L = s * 4096 + wave * 1024 + lane * 16;
                int row = L / RB;
                int col = (L % RB) ^ ((row & 7) << 4);
                gload_lds16(Wc + (size_t)(n0 + row) * XKK + k1 + col / 2,
                            &Ws[buf ^ 1][(s * 4096 + wave * 1024) / 2]);
            }
        }
        #pragma unroll
        for (int kk2 = 0; kk2 < 2; ++kk2) {
            s16x8 bfrag = *(const s16x8*)&Ws[buf][(wave * 16 + r16) * BK2 + ((kk2 * 32 + kg * 8) ^ swz)];
            #pragma unroll
            for (int i = 0; i < 8; ++i) {
                s16x8 afrag = *(const s16x8*)&As[buf][(i * 16 + r16) * BK2 + ((kk2 * 32 + kg * 8) ^ swz)];
                acc[i] = __builtin_amdgcn_mfma_f32_16x16x32_bf16(afrag, bfrag, acc[i], 0, 0, 0);
            }
        }
        __syncthreads();
        buf ^= 1;
    }
    {
        int n = n0 + wave * 16 + r16;
        float* Cz = gates + (size_t)z * B_ * 2048;
        #pragma unroll
        for (int i = 0; i < 8; ++i)
            #pragma unroll
            for (int r = 0; r < 4; ++r)
                Cz[(size_t)(i * 16 + kg * 4 + r) * 2048 + n] = acc[i][r];
    }

    // ---- completion counter: last of the 8 z-blocks for this ntile ----
    __syncthreads();                 // drain this block's global stores
    if (tid == 0) {
        __threadfence();             // release
        unsigned int old = __hip_atomic_fetch_add(&gcnt[ntile * 32], 1u,
                                __ATOMIC_ACQ_REL, __HIP_MEMORY_SCOPE_AGENT);
        int last = (old == 8u * (unsigned)(t + 1) - 1u);
        if (last) __threadfence();   // acquire: see all 8 slabs
        slast = last;
    }
    __syncthreads();
    if (slast) {
        const size_t slab = (size_t)B_ * 2048;
        const int d0 = ntile * 16;
        for (int k = tid; k < 2048; k += 256) {
            int b = k >> 4, dd = k & 15;
            int d = d0 + dd;
            if (dlen[b] <= t) {
                hstore[((size_t)t * B_ + b) * DD + d] = 0;   // fc masks this row
                continue;                                    // h, c, h_bf frozen
            }
            float gi = blstm[d], gf = blstm[512 + d];
            float gG = blstm[1024 + d], go = blstm[1536 + d];
            const float* gp = gates + (size_t)b * 2048 + n0 + (dd << 2);
            #pragma unroll
            for (int z2 = 0; z2 < 8; ++z2) {
                float4 v = *(const float4*)(gp + z2 * slab);
                gi += v.x; gf += v.y; gG += v.z; go += v.w;
            }
            int idx = (b << 9) + d;
            float cn = sigmoidf_(gf) * c[idx] + sigmoidf_(gi) * tanhf(gG);
            float hn = sigmoidf_(go) * tanhf(cn);
            unsigned short hb = f2bf(hn);
            hstore[((size_t)t * B_ + b) * DD + d] = hb;
            h[idx] = hn; c[idx] = cn;
            h_bf[idx] = hb;
        }
    }
}

// ---------------------------------------------------------------------------
// attn: fused scores + softmax + ctx + xcat fill. grid (2, 128), 256 threads.
// ---------------------------------------------------------------------------
template<int NS>
__global__ void attn_kernel(const unsigned short* __restrict__ efeat,
                            const float* __restrict__ proj, const float* __restrict__ battn,
                            const float* __restrict__ full_W, const float* __restrict__ full_b,
                            const int* __restrict__ si, const int* __restrict__ dlen,
                            const int* __restrict__ enc_cap, const float* __restrict__ emb_W,
                            const unsigned short* __restrict__ h_bf,
                            const unsigned short* __restrict__ encbf,
                            const float* __restrict__ encf, int use_bf,
                            float* __restrict__ alphas_out, unsigned short* __restrict__ xcat, int t)
{
    int b = blockIdx.y, x = blockIdx.x, tid = threadIdx.x;
    int wave = tid >> 6, lane = tid & 63;
    bool active = dlen[b] > t;
    if (!active) {
        if (x == 0 && tid < P_) alphas_out[((size_t)b * TT + t) * P_ + tid] = 0.f;
        return;
    }
    __shared__ float df[AA];
    __shared__ float wf[AA];
    __shared__ float sal[P_];
    __shared__ float red[8];
    const float* pz = proj + (size_t)b * PROJN;
    const size_t ps = (size_t)B_ * PROJN;
    for (int i = tid; i < AA; i += 256) {
        float v = battn[i];
        #pragma unroll
        for (int z = 0; z < NS; ++z) v += pz[z * ps + i];
        df[i] = v; wf[i] = full_W[i];
    }
    __syncthreads();
    int sb = si[b];
    float s = full_b[0];
    if (tid < P_) {
        const unsigned short* ef = efeat + ((size_t)sb * P_ + tid) * AA;
        #pragma unroll 8
        for (int e8 = 0; e8 < 64; ++e8) {
            s16x8 ev = *(const s16x8*)(ef + e8 * 8);
            #pragma unroll
            for (int j = 0; j < 8; ++j) {
                float v = bf2f((unsigned short)ev[j]) + df[e8 * 8 + j];
                v = v > 0.f ? v : 0.f;
                s = fmaf(v, wf[e8 * 8 + j], s);
            }
        }
    }
    float v = (tid < P_) ? s : -1e30f;
    float m = v;
    #pragma unroll
    for (int off = 32; off; off >>= 1) m = fmaxf(m, __shfl_down(m, off));
    if (lane == 0) red[wave] = m;
    __syncthreads();
    if (tid == 0) red[4] = fmaxf(fmaxf(red[0], red[1]), fmaxf(red[2], red[3]));
    __syncthreads();
    m = red[4];
    float e = (tid < P_) ? __expf(v - m) : 0.f;
    float ssum = e;
    #pragma unroll
    for (int off = 32; off; off >>= 1) ssum += __shfl_down(ssum, off);
    if (lane == 0) red[wave] = ssum;
    __syncthreads();
    if (tid == 0) red[5] = 1.0f / (red[0] + red[1] + red[2] + red[3]);
    __syncthreads();
    float al = e * red[5];
    if (tid < P_) sal[tid] = al;
    if (x == 0) {
        if (tid < P_) alphas_out[((size_t)b * TT + t) * P_ + tid] = al;
        int tok = enc_cap[sb * LL + t];
        for (int k = tid; k < EE; k += 256) {
            xcat[(size_t)b * XKK + k]        = f2bf(emb_W[(size_t)tok * EE + k]);
            xcat[(size_t)b * XKK + 2560 + k] = h_bf[b * DD + k];
        }
    }
    __syncthreads();

    int e0 = x * 1024 + tid * 4;
    float a0 = 0.f, a1 = 0.f, a2 = 0.f, a3 = 0.f;
    if (use_bf) {
        const unsigned short* base = encbf + (size_t)sb * P_ * ENCD + e0;
        #pragma unroll 7
        for (int p = 0; p < P_; ++p) {
            uint2 u = *(const uint2*)(base + (size_t)p * ENCD);
            float alp = sal[p];
            a0 = fmaf(alp, __uint_as_float(u.x << 16), a0);
            a1 = fmaf(alp, __uint_as_float(u.x & 0xffff0000u), a1);
            a2 = fmaf(alp, __uint_as_float(u.y << 16), a2);
            a3 = fmaf(alp, __uint_as_float(u.y & 0xffff0000u), a3);
        }
    } else {
        const float* base = encf + (size_t)sb * P_ * ENCD + e0;
        #pragma unroll 7
        for (int p = 0; p < P_; ++p) {
            float4 u = *(const float4*)(base + (size_t)p * ENCD);
            float alp = sal[p];
            a0 = fmaf(alp, u.x, a0); a1 = fmaf(alp, u.y, a1);
            a2 = fmaf(alp, u.z, a2); a3 = fmaf(alp, u.w, a3);
        }
    }
    int ei = AA + e0;
    float4 gl = *(const float4*)&battn[ei];
    #pragma unroll
    for (int z = 0; z < NS; ++z) {
        float4 gp = *(const float4*)&pz[z * ps + ei];
        gl.x += gp.x; gl.y += gp.y; gl.z += gp.z; gl.w += gp.w;
    }
    ushort4 xo;
    xo.x = f2bf(a0 * sigmoidf_(gl.x));
    xo.y = f2bf(a1 * sigmoidf_(gl.y));
    xo.z = f2bf(a2 * sigmoidf_(gl.z));
    xo.w = f2bf(a3 * sigmoidf_(gl.w));
    *(ushort4*)&xcat[(size_t)b * XKK + EE + e0] = xo;
}

// ---------------------------------------------------------------------------
// converts
// ---------------------------------------------------------------------------
__global__ void conv_bf16_kernel(const float* __restrict__ src, unsigned short* __restrict__ dst, int n4)
{
    for (int i = blockIdx.x * 256 + threadIdx.x; i < n4; i += gridDim.x * 256) {
        float4 v = ((const float4*)src)[i];
        ushort4 o;
        o.x = f2bf(v.x); o.y = f2bf(v.y); o.z = f2bf(v.z); o.w = f2bf(v.w);
        ((ushort4*)dst)[i] = o;
    }
}
__global__ void conv_wproj_kernel(const float* __restrict__ dec_W, const float* __restrict__ fbeta_W,
                                  unsigned short* __restrict__ dst)
{   // grid (2, 2560)
    int k = blockIdx.x * 256 + threadIdx.x, n = blockIdx.y;
    float v = (n < AA) ? dec_W[(size_t)n * DD + k] : fbeta_W[(size_t)(n - AA) * DD + k];
    dst[(size_t)n * DD + k] = f2bf(v);
}
__global__ void conv_wcat_perm_kernel(const float* __restrict__ Wih, const float* __restrict__ Whh,
                                      unsigned short* __restrict__ dst)
{   // grid (12, 2048): dst row pn <- orig gate row (pn&3)*512 + (pn>>2)
    int k = blockIdx.x * 256 + threadIdx.x, pn = blockIdx.y;
    int o = (pn & 3) * 512 + (pn >> 2);
    float v = (k < 2560) ? Wih[(size_t)o * 2560 + k] : Whh[(size_t)o * DD + (k - 2560)];
    dst[(size_t)pn * XKK + k] = f2bf(v);
}
__global__ void conv_fcw_kernel(const float* __restrict__ fc_W, unsigned short* __restrict__ dst)
{   // grid (2, 10048)
    int k = blockIdx.x * 256 + threadIdx.x, n = blockIdx.y;
    float v = (n < VV) ? fc_W[(size_t)n * DD + k] : 0.f;
    dst[(size_t)n * DD + k] = f2bf(v);
}

// ---------------------------------------------------------------------------
extern "C" void kernel_launch(void* const* d_in, const int* in_sizes, int n_in,
                              void* d_out, int out_size, void* d_ws, size_t ws_size,
                              hipStream_t stream)
{
    const float* encoder_out = (const float*)d_in[0];
    const int*   enc_cap     = (const int*)d_in[1];
    const int*   cap_len     = (const int*)d_in[2];
    const float* emb_W       = (const float*)d_in[3];
    const float* init_h_W    = (const float*)d_in[4];
    const float* init_h_b    = (const float*)d_in[5];
    const float* init_c_W    = (const float*)d_in[6];
    const float* init_c_b    = (const float*)d_in[7];
    const float* enc_attn_W  = (const float*)d_in[8];
    const float* enc_attn_b  = (const float*)d_in[9];
    const float* dec_attn_W  = (const float*)d_in[10];
    const float* dec_attn_b  = (const float*)d_in[11];
    const float* full_attn_W = (const float*)d_in[12];
    const float* full_attn_b = (const float*)d_in[13];
    const float* lstm_Wih    = (const float*)d_in[14];
    const float* lstm_Whh    = (const float*)d_in[15];
    const float* lstm_bih    = (const float*)d_in[16];
    const float* lstm_bhh    = (const float*)d_in[17];
    const float* fbeta_W     = (const float*)d_in[18];
    const float* fbeta_b     = (const float*)d_in[19];
    const float* fc_W        = (const float*)d_in[20];
    const float* fc_b        = (const float*)d_in[21];

    char* wsb = (char*)d_ws;
    int*   si     = (int*)(wsb + WS_SI);
    int*   dlen   = (int*)(wsb + WS_DLEN);
    float* battn  = (float*)(wsb + WS_BATTN);
    float* blstm  = (float*)(wsb + WS_BLSTM);
    float* means  = (float*)(wsb + WS_MEANS);
    unsigned int* gcnt = (unsigned int*)(wsb + WS_MEANS);   // reused post-init
    float* h      = (float*)(wsb + WS_H);
    float* c      = (float*)(wsb + WS_C);
    unsigned short* h_bf   = (unsigned short*)(wsb + WS_HBF);
    float* proj   = (float*)(wsb + WS_PROJ);
    unsigned short* xcat   = (unsigned short*)(wsb + WS_XCAT);
    float* gates  = (float*)(wsb + WS_GATES);
    unsigned short* hstore = (unsigned short*)(wsb + WS_HSTORE);
    unsigned short* wproj  = (unsigned short*)(wsb + WS_WPROJ);
    unsigned short* wcat   = (unsigned short*)(wsb + WS_WCAT);
    unsigned short* fcw    = (unsigned short*)(wsb + WS_FCW);
    unsigned short* wenc   = (unsigned short*)(wsb + WS_WENC);
    unsigned short* efeat  = (unsigned short*)(wsb + WS_EFEAT);
    unsigned short* encbf  = (unsigned short*)(wsb + WS_ENCBF);

    float* out      = (float*)d_out;
    float* out0     = out + OUT0_OFF;
    float* out_caps = out + OUT1_OFF;
    float* out_dlen = out + OUT2_OFF;
    float* alphas   = out + OUT3_OFF;
    float* out_sind = out + OUT4_OFF;

    const int use_encbf = (ws_size >= NEED_ENCBF) ? 1 : 0;

    // ---- setup ----
    sort_kernel<<<1, B_, 0, stream>>>(cap_len, enc_cap, si, dlen, out_caps, out_dlen, out_sind);
    bias_cat_kernel<<<10, 256, 0, stream>>>(dec_attn_b, fbeta_b, lstm_bih, lstm_bhh, battn, blstm);
    enc_mean_sorted<<<(B_ * ENCD) / 256, 256, 0, stream>>>(encoder_out, si, means);

    mfma_gemm<0, true, 32><<<dim3(DD / 64, 1, 1), 256, 0, stream>>>(
        means, init_h_W, init_h_b, nullptr, h, nullptr, ENCD, ENCD, DD, 0, DD);
    mfma_gemm<0, true, 32><<<dim3(DD / 64, 1, 1), 256, 0, stream>>>(
        means, init_c_W, init_c_b, nullptr, c, nullptr, ENCD, ENCD, DD, 0, DD);
    conv_bf16_kernel<<<64, 256, 0, stream>>>(h, h_bf, (B_ * DD) / 4);
    zero_gcnt_kernel<<<1, 64, 0, stream>>>(gcnt);   // after init GEMMs consumed means

    conv_wproj_kernel<<<dim3(2, PROJN), 256, 0, stream>>>(dec_attn_W, fbeta_W, wproj);
    conv_wcat_perm_kernel<<<dim3(12, 2048), 256, 0, stream>>>(lstm_Wih, lstm_Whh, wcat);
    conv_fcw_kernel<<<dim3(2, VPAD), 256, 0, stream>>>(fc_W, fcw);
    conv_bf16_kernel<<<256, 256, 0, stream>>>(enc_attn_W, wenc, (AA * ENCD) / 4);
    if (use_encbf)
        conv_bf16_kernel<<<2048, 256, 0, stream>>>(encoder_out, encbf, (B_ * P_ * ENCD) / 4);

    if (use_encbf)
        mfma_gemm<1, false, 64><<<dim3(AA / 64, (B_ * P_) / 128, 1), 256, 0, stream>>>(
            encbf, wenc, enc_attn_b, nullptr, nullptr, efeat, ENCD, ENCD, AA, 0, AA);
    else
        mfma_gemm<1, true, 32><<<dim3(AA / 64, (B_ * P_) / 128, 1), 256, 0, stream>>>(
            encoder_out, enc_attn_W, enc_attn_b, nullptr, nullptr, efeat, ENCD, ENCD, AA, 0, AA);

    // ---- decode loop: 3 dispatches/step ----
    for (int t = 0; t < TT; ++t) {
        // proj = h_bf @ [dec_attn|fbeta]^T : split-K x4 slabs (bias in consumers)
        mfma_gemm<0, false, 64><<<dim3(PROJN / 64, 1, 4), 256, 0, stream>>>(
            h_bf, wproj, nullptr, nullptr, proj, nullptr, DD, 128, PROJN, (long long)B_ * PROJN, PROJN);

        attn_kernel<4><<<dim3(2, B_), 256, 0, stream>>>(
            efeat, proj, battn, full_attn_W, full_attn_b, si, dlen, enc_cap, emb_W, h_bf,
            encbf, encoder_out, use_encbf, alphas, xcat, t);

        // gates GEMM (split-K x8, permuted W) + fine-grained fused pointwise
        gates_pw2_kernel<<<dim3(32, 1, 8), 256, 0, stream>>>(
            xcat, wcat, gates, blstm, dlen, h, c, h_bf, hstore, gcnt, t);
    }

    // fc over all steps: flat grid (t fast-varying shares W panel), swizzled LDS
    mfma_gemm<2, false, 64><<<dim3(TT, VPAD / 64, 1), 256, 0, stream>>>(
        hstore, fcw, fc_b, dlen, out0, nullptr, DD, DD, VV, 0, VV);
}

// Round 14
// 2808.613 us; speedup vs baseline: 1.2599x; 1.2599x over previous
//
#include <hip/hip_runtime.h>
#include <hip/hip_bf16.h>

// Problem dims
#define B_    128
#define P_    196
#define ENCD  2048
#define LL    50
#define VV    10000
#define AA    512
#define DD    512
#define EE    512
#define TT    49
#define XKK   3072    // E + ENC + D
#define PROJN 2560    // A + ENC
#define VPAD  10048   // V rounded up to 64

// Output layout (float offsets)
#define OUT0_OFF 0
#define OUT1_OFF 62720000
#define OUT2_OFF 62726400
#define OUT3_OFF 62726528
#define OUT4_OFF 63955840

// Workspace layout (BYTE offsets)
#define WS_SI      0ull
#define WS_DLEN    512ull
#define WS_BATTN   1024ull        // 2560 f32
#define WS_BLSTM   11264ull       // 2048 f32
#define WS_MEANS   19456ull       // [128][2048] f32 (init only)
#define WS_H       1068032ull     // [128][512] f32
#define WS_C       1330176ull
#define WS_HBF     1592320ull     // [128][512] bf16
#define WS_PROJ    1723392ull     // 4 slabs x [128][2560] f32
#define WS_XCAT    6966272ull     // [128][3072] bf16
#define WS_GATES   7752704ull     // 8 slabs x [128][2048] f32
#define WS_HSTORE  16141312ull    // [49*128][512] bf16
#define WS_WPROJ   22563840ull    // [2560][512] bf16
#define WS_WCAT    25185280ull    // [2048][3072] bf16
#define WS_FCW     37768192ull    // [10048][512] bf16
#define WS_WENC    48057344ull    // [512][2048] bf16
#define WS_EFEAT   50154496ull    // [25088][512] bf16
#define WS_ENCBF   75844608ull    // [128*196][2048] bf16
#define NEED_ENCBF 178605056ull

typedef __attribute__((ext_vector_type(4))) float f32x4;
typedef __attribute__((ext_vector_type(8))) short s16x8;

__device__ __forceinline__ float sigmoidf_(float x) { return 1.0f / (1.0f + __expf(-x)); }

__device__ __forceinline__ unsigned short f2bf(float x) {
    union { float f; unsigned int u; } v; v.f = x;
    unsigned int r = (v.u + 0x7FFFu + ((v.u >> 16) & 1u)) >> 16;
    return (unsigned short)r;
}
__device__ __forceinline__ float bf2f(unsigned short u) {
    return __uint_as_float(((unsigned int)u) << 16);
}

__device__ __forceinline__ void gload_lds16(const void* g, void* l) {
    __builtin_amdgcn_global_load_lds((const __attribute__((address_space(1))) void*)g,
                                     (__attribute__((address_space(3))) void*)l, 16, 0, 0);
}

// ---------------------------------------------------------------------------
// Stable descending argsort of cap_len (B=128), plus int-ish outputs
// ---------------------------------------------------------------------------
__global__ void sort_kernel(const int* __restrict__ cap_len, const int* __restrict__ enc_cap,
                            int* __restrict__ si, int* __restrict__ dlen,
                            float* __restrict__ out_caps, float* __restrict__ out_dlen,
                            float* __restrict__ out_sind)
{
    __shared__ int cl[B_];
    __shared__ int rank_to_idx[B_];
    int i = threadIdx.x;
    cl[i] = cap_len[i];
    __syncthreads();
    int my = cl[i];
    int r = 0;
    for (int j = 0; j < B_; ++j) {
        int oj = cl[j];
        if (oj > my || (oj == my && j < i)) ++r;
    }
    rank_to_idx[r] = i;
    __syncthreads();
    int src = rank_to_idx[i];
    si[i] = src;
    int dl = cl[src] - 1;
    dlen[i] = dl;
    out_dlen[i] = (float)dl;
    out_sind[i] = (float)src;
    for (int k = 0; k < LL; ++k) out_caps[i * LL + k] = (float)enc_cap[src * LL + k];
}

__global__ void bias_cat_kernel(const float* __restrict__ dec_b, const float* __restrict__ fbeta_b,
                                const float* __restrict__ bih, const float* __restrict__ bhh,
                                float* __restrict__ b_attn, float* __restrict__ b_lstm)
{
    int i = blockIdx.x * 256 + threadIdx.x;
    if (i < AA) b_attn[i] = dec_b[i];
    else if (i < PROJN) b_attn[i] = fbeta_b[i - AA];
    if (i < 2048) b_lstm[i] = bih[i] + bhh[i];
}

__global__ void enc_mean_sorted(const float* __restrict__ enc, const int* __restrict__ si,
                                float* __restrict__ means)
{
    int idx = blockIdx.x * 256 + threadIdx.x;   // B*ENC
    int b = idx >> 11, e = idx & 2047;
    const float* p = enc + (size_t)si[b] * P_ * ENCD + e;
    float s = 0.f;
    for (int q = 0; q < P_; ++q) s += p[(size_t)q * ENCD];
    means[idx] = s * (1.0f / 196.0f);
}

// ---------------------------------------------------------------------------
// bf16 MFMA GEMM, double-buffered LDS, one barrier per k-iter, templated BK.
// BK2==64: XOR-swizzled LDS (swizzled SOURCE via linear gload dest + swizzled read).
// MODE 0: f32 out; MODE 1: bf16 out; MODE 2: fc epilogue (grid (T, N/64)).
// CONV: f32 sources (BK2 must be 32, no swizzle).
// ---------------------------------------------------------------------------
template<int MODE, bool CONV, int BK2>
__launch_bounds__(256)
__global__ void mfma_gemm(const void* __restrict__ Av, const void* __restrict__ Wv,
                          const float* __restrict__ bias, const int* __restrict__ dlen,
                          float* __restrict__ Cf, unsigned short* __restrict__ Cbf,
                          int K, int KC, long long ldc, long long slabStride, int Nreal)
{
    constexpr int RB = BK2 * 2;               // bytes per tile row
    constexpr int AL = (128 * RB) / 4096;     // A gload passes
    constexpr int WL = (64 * RB) / 4096;      // W gload passes
    constexpr bool SW = (BK2 == 64);          // swizzle enable
    __shared__ __align__(16) unsigned short As[2][128 * BK2];
    __shared__ __align__(16) unsigned short Ws[2][64 * BK2];
    const int tid  = threadIdx.x;
    const int wave = tid >> 6, lane = tid & 63;
    const int m0 = (MODE == 2 ? blockIdx.x : blockIdx.y) * 128;
    const int n0 = (MODE == 2 ? blockIdx.y : blockIdx.x) * 64;
    const int z  = blockIdx.z;
    const int kbeg = z * KC;
    const int nt = KC / BK2;
    const int r16 = lane & 15, kg = lane >> 4;
    const int swz = SW ? ((r16 & 7) << 3) : 0;   // shorts

    f32x4 acc[8];
    #pragma unroll
    for (int i = 0; i < 8; ++i) acc[i] = f32x4{0.f, 0.f, 0.f, 0.f};

    const int c_arow = tid >> 1, c_acb = (tid & 1) * 16;
    const int c_wrow = tid >> 2, c_wcb = (tid & 3) * 8;

    int buf = 0;

    if constexpr (!CONV) {
        const unsigned short* A = (const unsigned short*)Av;
        const unsigned short* W = (const unsigned short*)Wv;
        #pragma unroll
        for (int s = 0; s < AL; ++s) {
            int L = s * 4096 + wave * 1024 + lane * 16;
            int row = L / RB;
            int col = (L % RB) ^ (SW ? ((row & 7) << 4) : 0);
            gload_lds16(A + (size_t)(m0 + row) * K + kbeg + col / 2,
                        &As[0][(s * 4096 + wave * 1024) / 2]);
        }
        #pragma unroll
        for (int s = 0; s < WL; ++s) {
            int L = s * 4096 + wave * 1024 + lane * 16;
            int row = L / RB;
            int col = (L % RB) ^ (SW ? ((row & 7) << 4) : 0);
            gload_lds16(W + (size_t)(n0 + row) * K + kbeg + col / 2,
                        &Ws[0][(s * 4096 + wave * 1024) / 2]);
        }
        __syncthreads();
        for (int it = 0; it < nt; ++it) {
            if (it + 1 < nt) {
                int k1 = kbeg + (it + 1) * BK2;
                #pragma unroll
                for (int s = 0; s < AL; ++s) {
                    int L = s * 4096 + wave * 1024 + lane * 16;
                    int row = L / RB;
                    int col = (L % RB) ^ (SW ? ((row & 7) << 4) : 0);
                    gload_lds16(A + (size_t)(m0 + row) * K + k1 + col / 2,
                                &As[buf ^ 1][(s * 4096 + wave * 1024) / 2]);
                }
                #pragma unroll
                for (int s = 0; s < WL; ++s) {
                    int L = s * 4096 + wave * 1024 + lane * 16;
                    int row = L / RB;
                    int col = (L % RB) ^ (SW ? ((row & 7) << 4) : 0);
                    gload_lds16(W + (size_t)(n0 + row) * K + k1 + col / 2,
                                &Ws[buf ^ 1][(s * 4096 + wave * 1024) / 2]);
                }
            }
            #pragma unroll
            for (int kk2 = 0; kk2 < BK2 / 32; ++kk2) {
                s16x8 bfrag = *(const s16x8*)&Ws[buf][(wave * 16 + r16) * BK2 + ((kk2 * 32 + kg * 8) ^ swz)];
                #pragma unroll
                for (int i = 0; i < 8; ++i) {
                    s16x8 afrag = *(const s16x8*)&As[buf][(i * 16 + r16) * BK2 + ((kk2 * 32 + kg * 8) ^ swz)];
                    acc[i] = __builtin_amdgcn_mfma_f32_16x16x32_bf16(afrag, bfrag, acc[i], 0, 0, 0);
                }
            }
            __syncthreads();
            buf ^= 1;
        }
    } else {
        static_assert(!CONV || BK2 == 32, "CONV path requires BK2==32");
        const float* A = (const float*)Av;
        const float* W = (const float*)Wv;
        float ra[16], rw[8];
        #pragma unroll
        for (int j = 0; j < 16; ++j) ra[j] = A[(size_t)(m0 + c_arow) * K + kbeg + c_acb + j];
        #pragma unroll
        for (int j = 0; j < 8; ++j)  rw[j] = W[(size_t)(n0 + c_wrow) * K + kbeg + c_wcb + j];
        {
            unsigned short t0[16], t1[8];
            #pragma unroll
            for (int j = 0; j < 16; ++j) t0[j] = f2bf(ra[j]);
            #pragma unroll
            for (int j = 0; j < 8; ++j)  t1[j] = f2bf(rw[j]);
            *(s16x8*)&As[0][c_arow * 32 + c_acb]     = *(s16x8*)&t0[0];
            *(s16x8*)&As[0][c_arow * 32 + c_acb + 8] = *(s16x8*)&t0[8];
            *(s16x8*)&Ws[0][c_wrow * 32 + c_wcb]     = *(s16x8*)&t1[0];
        }
        __syncthreads();
        for (int it = 0; it < nt; ++it) {
            float ra2[16], rw2[8];
            bool more = (it + 1 < nt);
            if (more) {
                int k1 = kbeg + (it + 1) * 32;
                #pragma unroll
                for (int j = 0; j < 16; ++j) ra2[j] = A[(size_t)(m0 + c_arow) * K + k1 + c_acb + j];
                #pragma unroll
                for (int j = 0; j < 8; ++j)  rw2[j] = W[(size_t)(n0 + c_wrow) * K + k1 + c_wcb + j];
            }
            s16x8 bfrag = *(const s16x8*)&Ws[buf][(wave * 16 + r16) * 32 + kg * 8];
            #pragma unroll
            for (int i = 0; i < 8; ++i) {
                s16x8 afrag = *(const s16x8*)&As[buf][(i * 16 + r16) * 32 + kg * 8];
                acc[i] = __builtin_amdgcn_mfma_f32_16x16x32_bf16(afrag, bfrag, acc[i], 0, 0, 0);
            }
            if (more) {
                unsigned short t0[16], t1[8];
                #pragma unroll
                for (int j = 0; j < 16; ++j) t0[j] = f2bf(ra2[j]);
                #pragma unroll
                for (int j = 0; j < 8; ++j)  t1[j] = f2bf(rw2[j]);
                *(s16x8*)&As[buf ^ 1][c_arow * 32 + c_acb]     = *(s16x8*)&t0[0];
                *(s16x8*)&As[buf ^ 1][c_arow * 32 + c_acb + 8] = *(s16x8*)&t0[8];
                *(s16x8*)&Ws[buf ^ 1][c_wrow * 32 + c_wcb]     = *(s16x8*)&t1[0];
            }
            __syncthreads();
            buf ^= 1;
        }
    }

    int n = n0 + wave * 16 + r16;
    float bv = 0.f;
    if (bias && z == 0) bv = (MODE == 2) ? (n < Nreal ? bias[n] : 0.f) : bias[n];
    float* Cz = Cf + (size_t)z * slabStride;
    #pragma unroll
    for (int i = 0; i < 8; ++i) {
        #pragma unroll
        for (int r = 0; r < 4; ++r) {
            int m = m0 + i * 16 + kg * 4 + r;
            float v = acc[i][r] + bv;
            if (MODE == 0) {
                Cz[(size_t)m * ldc + n] = v;
            } else if (MODE == 1) {
                Cbf[(size_t)m * ldc + n] = f2bf(v);
            } else {
                int bb = m & 127, tt2 = m >> 7;
                if (n < Nreal)
                    Cf[((size_t)bb * TT + tt2) * VV + n] = (dlen[bb] > tt2) ? v : 0.f;
            }
        }
    }
}

// ---------------------------------------------------------------------------
// attn: fused scores + softmax + ctx. grid (2, 128), 256 threads.
// xcat emb/h fill is done here ONLY for t==0 (pointwise owns it for t>0).
// ---------------------------------------------------------------------------
template<int NS>
__global__ void attn_kernel(const unsigned short* __restrict__ efeat,
                            const float* __restrict__ proj, const float* __restrict__ battn,
                            const float* __restrict__ full_W, const float* __restrict__ full_b,
                            const int* __restrict__ si, const int* __restrict__ dlen,
                            const int* __restrict__ enc_cap, const float* __restrict__ emb_W,
                            const unsigned short* __restrict__ h_bf,
                            const unsigned short* __restrict__ encbf,
                            const float* __restrict__ encf, int use_bf,
                            float* __restrict__ alphas_out, unsigned short* __restrict__ xcat, int t)
{
    int b = blockIdx.y, x = blockIdx.x, tid = threadIdx.x;
    int wave = tid >> 6, lane = tid & 63;
    bool active = dlen[b] > t;
    if (!active) {
        if (x == 0 && tid < P_) alphas_out[((size_t)b * TT + t) * P_ + tid] = 0.f;
        return;
    }
    __shared__ float df[AA];
    __shared__ float wf[AA];
    __shared__ float sal[P_];
    __shared__ float red[8];
    const float* pz = proj + (size_t)b * PROJN;
    const size_t ps = (size_t)B_ * PROJN;
    for (int i = tid; i < AA; i += 256) {
        float v = battn[i];
        #pragma unroll
        for (int z = 0; z < NS; ++z) v += pz[z * ps + i];
        df[i] = v; wf[i] = full_W[i];
    }
    __syncthreads();
    int sb = si[b];
    float s = full_b[0];
    if (tid < P_) {
        const unsigned short* ef = efeat + ((size_t)sb * P_ + tid) * AA;
        #pragma unroll 8
        for (int e8 = 0; e8 < 64; ++e8) {
            s16x8 ev = *(const s16x8*)(ef + e8 * 8);
            #pragma unroll
            for (int j = 0; j < 8; ++j) {
                float v = bf2f((unsigned short)ev[j]) + df[e8 * 8 + j];
                v = v > 0.f ? v : 0.f;
                s = fmaf(v, wf[e8 * 8 + j], s);
            }
        }
    }
    float v = (tid < P_) ? s : -1e30f;
    float m = v;
    #pragma unroll
    for (int off = 32; off; off >>= 1) m = fmaxf(m, __shfl_down(m, off));
    if (lane == 0) red[wave] = m;
    __syncthreads();
    if (tid == 0) red[4] = fmaxf(fmaxf(red[0], red[1]), fmaxf(red[2], red[3]));
    __syncthreads();
    m = red[4];
    float e = (tid < P_) ? __expf(v - m) : 0.f;
    float ssum = e;
    #pragma unroll
    for (int off = 32; off; off >>= 1) ssum += __shfl_down(ssum, off);
    if (lane == 0) red[wave] = ssum;
    __syncthreads();
    if (tid == 0) red[5] = 1.0f / (red[0] + red[1] + red[2] + red[3]);
    __syncthreads();
    float al = e * red[5];
    if (tid < P_) sal[tid] = al;
    if (x == 0) {
        if (tid < P_) alphas_out[((size_t)b * TT + t) * P_ + tid] = al;
        if (t == 0) {
            int tok = enc_cap[sb * LL];
            for (int k = tid; k < EE; k += 256) {
                xcat[(size_t)b * XKK + k]        = f2bf(emb_W[(size_t)tok * EE + k]);
                xcat[(size_t)b * XKK + 2560 + k] = h_bf[b * DD + k];
            }
        }
    }
    __syncthreads();

    int e0 = x * 1024 + tid * 4;
    float a0 = 0.f, a1 = 0.f, a2 = 0.f, a3 = 0.f;
    if (use_bf) {
        const unsigned short* base = encbf + (size_t)sb * P_ * ENCD + e0;
        #pragma unroll 7
        for (int p = 0; p < P_; ++p) {
            uint2 u = *(const uint2*)(base + (size_t)p * ENCD);
            float alp = sal[p];
            a0 = fmaf(alp, __uint_as_float(u.x << 16), a0);
            a1 = fmaf(alp, __uint_as_float(u.x & 0xffff0000u), a1);
            a2 = fmaf(alp, __uint_as_float(u.y << 16), a2);
            a3 = fmaf(alp, __uint_as_float(u.y & 0xffff0000u), a3);
        }
    } else {
        const float* base = encf + (size_t)sb * P_ * ENCD + e0;
        #pragma unroll 7
        for (int p = 0; p < P_; ++p) {
            float4 u = *(const float4*)(base + (size_t)p * ENCD);
            float alp = sal[p];
            a0 = fmaf(alp, u.x, a0); a1 = fmaf(alp, u.y, a1);
            a2 = fmaf(alp, u.z, a2); a3 = fmaf(alp, u.w, a3);
        }
    }
    int ei = AA + e0;
    float4 gl = *(const float4*)&battn[ei];
    #pragma unroll
    for (int z = 0; z < NS; ++z) {
        float4 gp = *(const float4*)&pz[z * ps + ei];
        gl.x += gp.x; gl.y += gp.y; gl.z += gp.z; gl.w += gp.w;
    }
    ushort4 xo;
    xo.x = f2bf(a0 * sigmoidf_(gl.x));
    xo.y = f2bf(a1 * sigmoidf_(gl.y));
    xo.z = f2bf(a2 * sigmoidf_(gl.z));
    xo.w = f2bf(a3 * sigmoidf_(gl.w));
    *(ushort4*)&xcat[(size_t)b * XKK + EE + e0] = xo;
}

// ---------------------------------------------------------------------------
// LSTM pointwise for step (t-1): sum NS gate slabs + bias -> h,c update.
// Also fills xcat emb (for step t) and xcat h-slot.
// ---------------------------------------------------------------------------
template<int NS>
__global__ void pointwise_kernel(const float* __restrict__ gates, const float* __restrict__ blstm,
                                 const int* __restrict__ dlen,
                                 const int* __restrict__ si, const int* __restrict__ enc_cap,
                                 const float* __restrict__ emb_W,
                                 float* __restrict__ h, float* __restrict__ c,
                                 unsigned short* __restrict__ h_bf, unsigned short* __restrict__ hstore,
                                 unsigned short* __restrict__ xcat, int t)
{
    int idx = blockIdx.x * 256 + threadIdx.x;
    int b = idx >> 9, d = idx & 511;
    bool act = dlen[b] > (t - 1);
    unsigned short hb;
    if (!act) {
        hstore[((size_t)(t - 1) * B_ + b) * DD + d] = 0;   // fc masks this row anyway
        hb = h_bf[idx];                                     // frozen
    } else {
        const size_t slab = (size_t)B_ * 2048;
        const float* g = gates + (size_t)b * 2048;
        float gi = blstm[d], gf = blstm[512 + d], gg = blstm[1024 + d], go = blstm[1536 + d];
        #pragma unroll
        for (int z = 0; z < NS; ++z) {
            gi += g[z * slab + d];
            gf += g[z * slab + 512 + d];
            gg += g[z * slab + 1024 + d];
            go += g[z * slab + 1536 + d];
        }
        float cn = sigmoidf_(gf) * c[idx] + sigmoidf_(gi) * tanhf(gg);
        float hn = sigmoidf_(go) * tanhf(cn);
        hb = f2bf(hn);
        hstore[((size_t)(t - 1) * B_ + b) * DD + d] = hb;
        h[idx] = hn; c[idx] = cn;
        h_bf[idx] = hb;
    }
    if (t < TT) {
        // fill xcat for step t: emb + h slots (d spans exactly EE)
        int tok = enc_cap[si[b] * LL + t];
        xcat[(size_t)b * XKK + d]        = f2bf(emb_W[(size_t)tok * EE + d]);
        xcat[(size_t)b * XKK + 2560 + d] = hb;
    }
}

// ---------------------------------------------------------------------------
// converts
// ---------------------------------------------------------------------------
__global__ void conv_bf16_kernel(const float* __restrict__ src, unsigned short* __restrict__ dst, int n4)
{
    for (int i = blockIdx.x * 256 + threadIdx.x; i < n4; i += gridDim.x * 256) {
        float4 v = ((const float4*)src)[i];
        ushort4 o;
        o.x = f2bf(v.x); o.y = f2bf(v.y); o.z = f2bf(v.z); o.w = f2bf(v.w);
        ((ushort4*)dst)[i] = o;
    }
}
__global__ void conv_wproj_kernel(const float* __restrict__ dec_W, const float* __restrict__ fbeta_W,
                                  unsigned short* __restrict__ dst)
{   // grid (2, 2560)
    int k = blockIdx.x * 256 + threadIdx.x, n = blockIdx.y;
    float v = (n < AA) ? dec_W[(size_t)n * DD + k] : fbeta_W[(size_t)(n - AA) * DD + k];
    dst[(size_t)n * DD + k] = f2bf(v);
}
__global__ void conv_wcat_kernel(const float* __restrict__ Wih, const float* __restrict__ Whh,
                                 unsigned short* __restrict__ dst)
{   // grid (12, 2048)
    int k = blockIdx.x * 256 + threadIdx.x, n = blockIdx.y;
    float v = (k < 2560) ? Wih[(size_t)n * 2560 + k] : Whh[(size_t)n * DD + (k - 2560)];
    dst[(size_t)n * XKK + k] = f2bf(v);
}
__global__ void conv_fcw_kernel(const float* __restrict__ fc_W, unsigned short* __restrict__ dst)
{   // grid (2, 10048)
    int k = blockIdx.x * 256 + threadIdx.x, n = blockIdx.y;
    float v = (n < VV) ? fc_W[(size_t)n * DD + k] : 0.f;
    dst[(size_t)n * DD + k] = f2bf(v);
}

// ---------------------------------------------------------------------------
extern "C" void kernel_launch(void* const* d_in, const int* in_sizes, int n_in,
                              void* d_out, int out_size, void* d_ws, size_t ws_size,
                              hipStream_t stream)
{
    const float* encoder_out = (const float*)d_in[0];
    const int*   enc_cap     = (const int*)d_in[1];
    const int*   cap_len     = (const int*)d_in[2];
    const float* emb_W       = (const float*)d_in[3];
    const float* init_h_W    = (const float*)d_in[4];
    const float* init_h_b    = (const float*)d_in[5];
    const float* init_c_W    = (const float*)d_in[6];
    const float* init_c_b    = (const float*)d_in[7];
    const float* enc_attn_W  = (const float*)d_in[8];
    const float* enc_attn_b  = (const float*)d_in[9];
    const float* dec_attn_W  = (const float*)d_in[10];
    const float* dec_attn_b  = (const float*)d_in[11];
    const float* full_attn_W = (const float*)d_in[12];
    const float* full_attn_b = (const float*)d_in[13];
    const float* lstm_Wih    = (const float*)d_in[14];
    const float* lstm_Whh    = (const float*)d_in[15];
    const float* lstm_bih    = (const float*)d_in[16];
    const float* lstm_bhh    = (const float*)d_in[17];
    const float* fbeta_W     = (const float*)d_in[18];
    const float* fbeta_b     = (const float*)d_in[19];
    const float* fc_W        = (const float*)d_in[20];
    const float* fc_b        = (const float*)d_in[21];

    char* wsb = (char*)d_ws;
    int*   si     = (int*)(wsb + WS_SI);
    int*   dlen   = (int*)(wsb + WS_DLEN);
    float* battn  = (float*)(wsb + WS_BATTN);
    float* blstm  = (float*)(wsb + WS_BLSTM);
    float* means  = (float*)(wsb + WS_MEANS);
    float* h      = (float*)(wsb + WS_H);
    float* c      = (float*)(wsb + WS_C);
    unsigned short* h_bf   = (unsigned short*)(wsb + WS_HBF);
    float* proj   = (float*)(wsb + WS_PROJ);
    unsigned short* xcat   = (unsigned short*)(wsb + WS_XCAT);
    float* gates  = (float*)(wsb + WS_GATES);
    unsigned short* hstore = (unsigned short*)(wsb + WS_HSTORE);
    unsigned short* wproj  = (unsigned short*)(wsb + WS_WPROJ);
    unsigned short* wcat   = (unsigned short*)(wsb + WS_WCAT);
    unsigned short* fcw    = (unsigned short*)(wsb + WS_FCW);
    unsigned short* wenc   = (unsigned short*)(wsb + WS_WENC);
    unsigned short* efeat  = (unsigned short*)(wsb + WS_EFEAT);
    unsigned short* encbf  = (unsigned short*)(wsb + WS_ENCBF);

    float* out      = (float*)d_out;
    float* out0     = out + OUT0_OFF;
    float* out_caps = out + OUT1_OFF;
    float* out_dlen = out + OUT2_OFF;
    float* alphas   = out + OUT3_OFF;
    float* out_sind = out + OUT4_OFF;

    const int use_encbf = (ws_size >= NEED_ENCBF) ? 1 : 0;

    // ---- setup ----
    sort_kernel<<<1, B_, 0, stream>>>(cap_len, enc_cap, si, dlen, out_caps, out_dlen, out_sind);
    bias_cat_kernel<<<10, 256, 0, stream>>>(dec_attn_b, fbeta_b, lstm_bih, lstm_bhh, battn, blstm);
    enc_mean_sorted<<<(B_ * ENCD) / 256, 256, 0, stream>>>(encoder_out, si, means);

    mfma_gemm<0, true, 32><<<dim3(DD / 64, 1, 1), 256, 0, stream>>>(
        means, init_h_W, init_h_b, nullptr, h, nullptr, ENCD, ENCD, DD, 0, DD);
    mfma_gemm<0, true, 32><<<dim3(DD / 64, 1, 1), 256, 0, stream>>>(
        means, init_c_W, init_c_b, nullptr, c, nullptr, ENCD, ENCD, DD, 0, DD);
    conv_bf16_kernel<<<64, 256, 0, stream>>>(h, h_bf, (B_ * DD) / 4);

    conv_wproj_kernel<<<dim3(2, PROJN), 256, 0, stream>>>(dec_attn_W, fbeta_W, wproj);
    conv_wcat_kernel<<<dim3(12, 2048), 256, 0, stream>>>(lstm_Wih, lstm_Whh, wcat);
    conv_fcw_kernel<<<dim3(2, VPAD), 256, 0, stream>>>(fc_W, fcw);
    conv_bf16_kernel<<<256, 256, 0, stream>>>(enc_attn_W, wenc, (AA * ENCD) / 4);
    if (use_encbf)
        conv_bf16_kernel<<<2048, 256, 0, stream>>>(encoder_out, encbf, (B_ * P_ * ENCD) / 4);

    if (use_encbf)
        mfma_gemm<1, false, 64><<<dim3(AA / 64, (B_ * P_) / 128, 1), 256, 0, stream>>>(
            encbf, wenc, enc_attn_b, nullptr, nullptr, efeat, ENCD, ENCD, AA, 0, AA);
    else
        mfma_gemm<1, true, 32><<<dim3(AA / 64, (B_ * P_) / 128, 1), 256, 0, stream>>>(
            encoder_out, enc_attn_W, enc_attn_b, nullptr, nullptr, efeat, ENCD, ENCD, AA, 0, AA);

    // ---- decode loop: 4 dispatches/step ----
    for (int t = 0; t < TT; ++t) {
        if (t > 0)
            pointwise_kernel<8><<<(B_ * DD) / 256, 256, 0, stream>>>(
                gates, blstm, dlen, si, enc_cap, emb_W, h, c, h_bf, hstore, xcat, t);

        // proj = h_bf @ [dec_attn|fbeta]^T : split-K x4 slabs (bias in consumers)
        mfma_gemm<0, false, 64><<<dim3(PROJN / 64, 1, 4), 256, 0, stream>>>(
            h_bf, wproj, nullptr, nullptr, proj, nullptr, DD, 128, PROJN, (long long)B_ * PROJN, PROJN);

        attn_kernel<4><<<dim3(2, B_), 256, 0, stream>>>(
            efeat, proj, battn, full_attn_W, full_attn_b, si, dlen, enc_cap, emb_W, h_bf,
            encbf, encoder_out, use_encbf, alphas, xcat, t);

        // gates = x_cat @ [Wih|Whh]^T : split-K x8 slabs (bias in pointwise)
        mfma_gemm<0, false, 64><<<dim3(2048 / 64, 1, 8), 256, 0, stream>>>(
            xcat, wcat, nullptr, nullptr, gates, nullptr, XKK, 384, 2048, (long long)B_ * 2048, 2048);
    }
    pointwise_kernel<8><<<(B_ * DD) / 256, 256, 0, stream>>>(
        gates, blstm, dlen, si, enc_cap, emb_W, h, c, h_bf, hstore, xcat, TT);

    // fc over all steps: flat grid (t fast-varying shares W panel), swizzled LDS
    mfma_gemm<2, false, 64><<<dim3(TT, VPAD / 64, 1), 256, 0, stream>>>(
        hstore, fcw, fc_b, dlen, out0, nullptr, DD, DD, VV, 0, VV);
}

// Round 15
// 2801.185 us; speedup vs baseline: 1.2633x; 1.0027x over previous
//
#include <hip/hip_runtime.h>
#include <hip/hip_bf16.h>

// Problem dims
#define B_    128
#define P_    196
#define ENCD  2048
#define LL    50
#define VV    10000
#define AA    512
#define DD    512
#define EE    512
#define TT    49
#define XKK   3072    // E + ENC + D
#define PROJN 2560    // A + ENC
#define VPAD  10048   // V rounded up to 64

// Output layout (float offsets)
#define OUT0_OFF 0
#define OUT1_OFF 62720000
#define OUT2_OFF 62726400
#define OUT3_OFF 62726528
#define OUT4_OFF 63955840

// Workspace layout (BYTE offsets)
#define WS_SI      0ull
#define WS_DLEN    512ull
#define WS_BATTN   1024ull        // 2560 f32
#define WS_BLSTM   11264ull       // 2048 f32
#define WS_MEANS   19456ull       // [128][2048] f32 (init only)
#define WS_H       1068032ull     // [128][512] f32
#define WS_C       1330176ull
#define WS_HBF     1592320ull     // [128][512] bf16
#define WS_PROJ    1723392ull     // 4 slabs x [128][2560] f32
#define WS_XCAT    6966272ull     // [128][3072] bf16
#define WS_GATES   7752704ull     // 8 slabs x [128][2048] f32
#define WS_HSTORE  16141312ull    // [49*128][512] bf16
#define WS_WPROJ   22563840ull    // [2560][512] bf16
#define WS_WCAT    25185280ull    // [2048][3072] bf16
#define WS_FCW     37768192ull    // [10048][512] bf16
#define WS_WENC    48057344ull    // [512][2048] bf16
#define WS_EFEAT   50154496ull    // [25088][512] bf16
#define WS_ENCBF   75844608ull    // [128*196][2048] bf16
#define NEED_ENCBF 178605056ull

typedef __attribute__((ext_vector_type(4))) float f32x4;
typedef __attribute__((ext_vector_type(8))) short s16x8;

__device__ __forceinline__ float sigmoidf_(float x) { return 1.0f / (1.0f + __expf(-x)); }

__device__ __forceinline__ unsigned short f2bf(float x) {
    union { float f; unsigned int u; } v; v.f = x;
    unsigned int r = (v.u + 0x7FFFu + ((v.u >> 16) & 1u)) >> 16;
    return (unsigned short)r;
}
__device__ __forceinline__ float bf2f(unsigned short u) {
    return __uint_as_float(((unsigned int)u) << 16);
}

__device__ __forceinline__ void gload_lds16(const void* g, void* l) {
    __builtin_amdgcn_global_load_lds((const __attribute__((address_space(1))) void*)g,
                                     (__attribute__((address_space(3))) void*)l, 16, 0, 0);
}

// ---------------------------------------------------------------------------
// Stable descending argsort of cap_len (B=128), plus int-ish outputs
// ---------------------------------------------------------------------------
__global__ void sort_kernel(const int* __restrict__ cap_len, const int* __restrict__ enc_cap,
                            int* __restrict__ si, int* __restrict__ dlen,
                            float* __restrict__ out_caps, float* __restrict__ out_dlen,
                            float* __restrict__ out_sind)
{
    __shared__ int cl[B_];
    __shared__ int rank_to_idx[B_];
    int i = threadIdx.x;
    cl[i] = cap_len[i];
    __syncthreads();
    int my = cl[i];
    int r = 0;
    for (int j = 0; j < B_; ++j) {
        int oj = cl[j];
        if (oj > my || (oj == my && j < i)) ++r;
    }
    rank_to_idx[r] = i;
    __syncthreads();
    int src = rank_to_idx[i];
    si[i] = src;
    int dl = cl[src] - 1;
    dlen[i] = dl;
    out_dlen[i] = (float)dl;
    out_sind[i] = (float)src;
    for (int k = 0; k < LL; ++k) out_caps[i * LL + k] = (float)enc_cap[src * LL + k];
}

__global__ void bias_cat_kernel(const float* __restrict__ dec_b, const float* __restrict__ fbeta_b,
                                const float* __restrict__ bih, const float* __restrict__ bhh,
                                float* __restrict__ b_attn, float* __restrict__ b_lstm)
{
    int i = blockIdx.x * 256 + threadIdx.x;
    if (i < AA) b_attn[i] = dec_b[i];
    else if (i < PROJN) b_attn[i] = fbeta_b[i - AA];
    if (i < 2048) b_lstm[i] = bih[i] + bhh[i];
}

__global__ void enc_mean_sorted(const float* __restrict__ enc, const int* __restrict__ si,
                                float* __restrict__ means)
{
    int idx = blockIdx.x * 256 + threadIdx.x;   // B*ENC
    int b = idx >> 11, e = idx & 2047;
    const float* p = enc + (size_t)si[b] * P_ * ENCD + e;
    float s = 0.f;
    for (int q = 0; q < P_; ++q) s += p[(size_t)q * ENCD];
    means[idx] = s * (1.0f / 196.0f);
}

// ---------------------------------------------------------------------------
// bf16 MFMA GEMM, double-buffered LDS, one barrier per k-iter, templated BK.
// BK2==64: XOR-swizzled LDS (swizzled SOURCE via linear gload dest + swizzled read).
// MODE 0: f32 out; MODE 1: bf16 out;
// MODE 2: fc epilogue — 1D grid 8000 with XCD 2D-region swizzle: id%8 = XCD,
//         each XCD owns a (t-half x ntile-quarter) region, t-minor order, so
//         its W panel + cycling A range stay resident in its private L2.
// CONV: f32 sources (BK2 must be 32, no swizzle).
// ---------------------------------------------------------------------------
template<int MODE, bool CONV, int BK2>
__launch_bounds__(256)
__global__ void mfma_gemm(const void* __restrict__ Av, const void* __restrict__ Wv,
                          const float* __restrict__ bias, const int* __restrict__ dlen,
                          float* __restrict__ Cf, unsigned short* __restrict__ Cbf,
                          int K, int KC, long long ldc, long long slabStride, int Nreal)
{
    constexpr int RB = BK2 * 2;               // bytes per tile row
    constexpr int AL = (128 * RB) / 4096;     // A gload passes
    constexpr int WL = (64 * RB) / 4096;      // W gload passes
    constexpr bool SW = (BK2 == 64);          // swizzle enable
    __shared__ __align__(16) unsigned short As[2][128 * BK2];
    __shared__ __align__(16) unsigned short Ws[2][64 * BK2];
    const int tid  = threadIdx.x;
    const int wave = tid >> 6, lane = tid & 63;

    int m0, n0;
    if constexpr (MODE == 2) {
        // XCD 2D-region swizzle over (t, ntile) = (49, 157)
        int id = blockIdx.x;
        int k = id & 7, s = id >> 3;          // XCD, within-XCD sequence
        int kt = k >> 2, kn = k & 3;
        int tn   = kt ? 24 : 25;              // t-range size
        int t0   = kt ? 25 : 0;
        int ncnt = (kn == 3) ? 37 : 40;       // ntile-range size
        int nq   = s / tn;
        if (nq >= ncnt) return;
        m0 = (t0 + s % tn) * 128;
        n0 = (kn * 40 + nq) * 64;
    } else {
        m0 = blockIdx.y * 128;
        n0 = blockIdx.x * 64;
    }
    const int z  = blockIdx.z;
    const int kbeg = z * KC;
    const int nt = KC / BK2;
    const int r16 = lane & 15, kg = lane >> 4;
    const int swz = SW ? ((r16 & 7) << 3) : 0;   // shorts

    f32x4 acc[8];
    #pragma unroll
    for (int i = 0; i < 8; ++i) acc[i] = f32x4{0.f, 0.f, 0.f, 0.f};

    const int c_arow = tid >> 1, c_acb = (tid & 1) * 16;
    const int c_wrow = tid >> 2, c_wcb = (tid & 3) * 8;

    int buf = 0;

    if constexpr (!CONV) {
        const unsigned short* A = (const unsigned short*)Av;
        const unsigned short* W = (const unsigned short*)Wv;
        #pragma unroll
        for (int s = 0; s < AL; ++s) {
            int L = s * 4096 + wave * 1024 + lane * 16;
            int row = L / RB;
            int col = (L % RB) ^ (SW ? ((row & 7) << 4) : 0);
            gload_lds16(A + (size_t)(m0 + row) * K + kbeg + col / 2,
                        &As[0][(s * 4096 + wave * 1024) / 2]);
        }
        #pragma unroll
        for (int s = 0; s < WL; ++s) {
            int L = s * 4096 + wave * 1024 + lane * 16;
            int row = L / RB;
            int col = (L % RB) ^ (SW ? ((row & 7) << 4) : 0);
            gload_lds16(W + (size_t)(n0 + row) * K + kbeg + col / 2,
                        &Ws[0][(s * 4096 + wave * 1024) / 2]);
        }
        __syncthreads();
        for (int it = 0; it < nt; ++it) {
            if (it + 1 < nt) {
                int k1 = kbeg + (it + 1) * BK2;
                #pragma unroll
                for (int s = 0; s < AL; ++s) {
                    int L = s * 4096 + wave * 1024 + lane * 16;
                    int row = L / RB;
                    int col = (L % RB) ^ (SW ? ((row & 7) << 4) : 0);
                    gload_lds16(A + (size_t)(m0 + row) * K + k1 + col / 2,
                                &As[buf ^ 1][(s * 4096 + wave * 1024) / 2]);
                }
                #pragma unroll
                for (int s = 0; s < WL; ++s) {
                    int L = s * 4096 + wave * 1024 + lane * 16;
                    int row = L / RB;
                    int col = (L % RB) ^ (SW ? ((row & 7) << 4) : 0);
                    gload_lds16(W + (size_t)(n0 + row) * K + k1 + col / 2,
                                &Ws[buf ^ 1][(s * 4096 + wave * 1024) / 2]);
                }
            }
            #pragma unroll
            for (int kk2 = 0; kk2 < BK2 / 32; ++kk2) {
                s16x8 bfrag = *(const s16x8*)&Ws[buf][(wave * 16 + r16) * BK2 + ((kk2 * 32 + kg * 8) ^ swz)];
                #pragma unroll
                for (int i = 0; i < 8; ++i) {
                    s16x8 afrag = *(const s16x8*)&As[buf][(i * 16 + r16) * BK2 + ((kk2 * 32 + kg * 8) ^ swz)];
                    acc[i] = __builtin_amdgcn_mfma_f32_16x16x32_bf16(afrag, bfrag, acc[i], 0, 0, 0);
                }
            }
            __syncthreads();
            buf ^= 1;
        }
    } else {
        static_assert(!CONV || BK2 == 32, "CONV path requires BK2==32");
        const float* A = (const float*)Av;
        const float* W = (const float*)Wv;
        float ra[16], rw[8];
        #pragma unroll
        for (int j = 0; j < 16; ++j) ra[j] = A[(size_t)(m0 + c_arow) * K + kbeg + c_acb + j];
        #pragma unroll
        for (int j = 0; j < 8; ++j)  rw[j] = W[(size_t)(n0 + c_wrow) * K + kbeg + c_wcb + j];
        {
            unsigned short t0[16], t1[8];
            #pragma unroll
            for (int j = 0; j < 16; ++j) t0[j] = f2bf(ra[j]);
            #pragma unroll
            for (int j = 0; j < 8; ++j)  t1[j] = f2bf(rw[j]);
            *(s16x8*)&As[0][c_arow * 32 + c_acb]     = *(s16x8*)&t0[0];
            *(s16x8*)&As[0][c_arow * 32 + c_acb + 8] = *(s16x8*)&t0[8];
            *(s16x8*)&Ws[0][c_wrow * 32 + c_wcb]     = *(s16x8*)&t1[0];
        }
        __syncthreads();
        for (int it = 0; it < nt; ++it) {
            float ra2[16], rw2[8];
            bool more = (it + 1 < nt);
            if (more) {
                int k1 = kbeg + (it + 1) * 32;
                #pragma unroll
                for (int j = 0; j < 16; ++j) ra2[j] = A[(size_t)(m0 + c_arow) * K + k1 + c_acb + j];
                #pragma unroll
                for (int j = 0; j < 8; ++j)  rw2[j] = W[(size_t)(n0 + c_wrow) * K + k1 + c_wcb + j];
            }
            s16x8 bfrag = *(const s16x8*)&Ws[buf][(wave * 16 + r16) * 32 + kg * 8];
            #pragma unroll
            for (int i = 0; i < 8; ++i) {
                s16x8 afrag = *(const s16x8*)&As[buf][(i * 16 + r16) * 32 + kg * 8];
                acc[i] = __builtin_amdgcn_mfma_f32_16x16x32_bf16(afrag, bfrag, acc[i], 0, 0, 0);
            }
            if (more) {
                unsigned short t0[16], t1[8];
                #pragma unroll
                for (int j = 0; j < 16; ++j) t0[j] = f2bf(ra2[j]);
                #pragma unroll
                for (int j = 0; j < 8; ++j)  t1[j] = f2bf(rw2[j]);
                *(s16x8*)&As[buf ^ 1][c_arow * 32 + c_acb]     = *(s16x8*)&t0[0];
                *(s16x8*)&As[buf ^ 1][c_arow * 32 + c_acb + 8] = *(s16x8*)&t0[8];
                *(s16x8*)&Ws[buf ^ 1][c_wrow * 32 + c_wcb]     = *(s16x8*)&t1[0];
            }
            __syncthreads();
            buf ^= 1;
        }
    }

    int n = n0 + wave * 16 + r16;
    float bv = 0.f;
    if (bias && z == 0) bv = (MODE == 2) ? (n < Nreal ? bias[n] : 0.f) : bias[n];
    float* Cz = Cf + (size_t)z * slabStride;
    #pragma unroll
    for (int i = 0; i < 8; ++i) {
        #pragma unroll
        for (int r = 0; r < 4; ++r) {
            int m = m0 + i * 16 + kg * 4 + r;
            float v = acc[i][r] + bv;
            if (MODE == 0) {
                Cz[(size_t)m * ldc + n] = v;
            } else if (MODE == 1) {
                Cbf[(size_t)m * ldc + n] = f2bf(v);
            } else {
                int bb = m & 127, tt2 = m >> 7;
                if (n < Nreal)
                    Cf[((size_t)bb * TT + tt2) * VV + n] = (dlen[bb] > tt2) ? v : 0.f;
            }
        }
    }
}

// ---------------------------------------------------------------------------
// attn: fused scores + softmax + ctx. grid (2, 128), 256 threads.
// xcat emb/h fill is done here ONLY for t==0 (pointwise owns it for t>0).
// ---------------------------------------------------------------------------
template<int NS>
__global__ void attn_kernel(const unsigned short* __restrict__ efeat,
                            const float* __restrict__ proj, const float* __restrict__ battn,
                            const float* __restrict__ full_W, const float* __restrict__ full_b,
                            const int* __restrict__ si, const int* __restrict__ dlen,
                            const int* __restrict__ enc_cap, const float* __restrict__ emb_W,
                            const unsigned short* __restrict__ h_bf,
                            const unsigned short* __restrict__ encbf,
                            const float* __restrict__ encf, int use_bf,
                            float* __restrict__ alphas_out, unsigned short* __restrict__ xcat, int t)
{
    int b = blockIdx.y, x = blockIdx.x, tid = threadIdx.x;
    int wave = tid >> 6, lane = tid & 63;
    bool active = dlen[b] > t;
    if (!active) {
        if (x == 0 && tid < P_) alphas_out[((size_t)b * TT + t) * P_ + tid] = 0.f;
        return;
    }
    __shared__ float df[AA];
    __shared__ float wf[AA];
    __shared__ float sal[P_];
    __shared__ float red[8];
    const float* pz = proj + (size_t)b * PROJN;
    const size_t ps = (size_t)B_ * PROJN;
    for (int i = tid; i < AA; i += 256) {
        float v = battn[i];
        #pragma unroll
        for (int z = 0; z < NS; ++z) v += pz[z * ps + i];
        df[i] = v; wf[i] = full_W[i];
    }
    __syncthreads();
    int sb = si[b];
    float s = full_b[0];
    if (tid < P_) {
        const unsigned short* ef = efeat + ((size_t)sb * P_ + tid) * AA;
        #pragma unroll 8
        for (int e8 = 0; e8 < 64; ++e8) {
            s16x8 ev = *(const s16x8*)(ef + e8 * 8);
            #pragma unroll
            for (int j = 0; j < 8; ++j) {
                float v = bf2f((unsigned short)ev[j]) + df[e8 * 8 + j];
                v = v > 0.f ? v : 0.f;
                s = fmaf(v, wf[e8 * 8 + j], s);
            }
        }
    }
    float v = (tid < P_) ? s : -1e30f;
    float m = v;
    #pragma unroll
    for (int off = 32; off; off >>= 1) m = fmaxf(m, __shfl_down(m, off));
    if (lane == 0) red[wave] = m;
    __syncthreads();
    if (tid == 0) red[4] = fmaxf(fmaxf(red[0], red[1]), fmaxf(red[2], red[3]));
    __syncthreads();
    m = red[4];
    float e = (tid < P_) ? __expf(v - m) : 0.f;
    float ssum = e;
    #pragma unroll
    for (int off = 32; off; off >>= 1) ssum += __shfl_down(ssum, off);
    if (lane == 0) red[wave] = ssum;
    __syncthreads();
    if (tid == 0) red[5] = 1.0f / (red[0] + red[1] + red[2] + red[3]);
    __syncthreads();
    float al = e * red[5];
    if (tid < P_) sal[tid] = al;
    if (x == 0) {
        if (tid < P_) alphas_out[((size_t)b * TT + t) * P_ + tid] = al;
        if (t == 0) {
            int tok = enc_cap[sb * LL];
            for (int k = tid; k < EE; k += 256) {
                xcat[(size_t)b * XKK + k]        = f2bf(emb_W[(size_t)tok * EE + k]);
                xcat[(size_t)b * XKK + 2560 + k] = h_bf[b * DD + k];
            }
        }
    }
    __syncthreads();

    int e0 = x * 1024 + tid * 4;
    float a0 = 0.f, a1 = 0.f, a2 = 0.f, a3 = 0.f;
    if (use_bf) {
        const unsigned short* base = encbf + (size_t)sb * P_ * ENCD + e0;
        #pragma unroll 7
        for (int p = 0; p < P_; ++p) {
            uint2 u = *(const uint2*)(base + (size_t)p * ENCD);
            float alp = sal[p];
            a0 = fmaf(alp, __uint_as_float(u.x << 16), a0);
            a1 = fmaf(alp, __uint_as_float(u.x & 0xffff0000u), a1);
            a2 = fmaf(alp, __uint_as_float(u.y << 16), a2);
            a3 = fmaf(alp, __uint_as_float(u.y & 0xffff0000u), a3);
        }
    } else {
        const float* base = encf + (size_t)sb * P_ * ENCD + e0;
        #pragma unroll 7
        for (int p = 0; p < P_; ++p) {
            float4 u = *(const float4*)(base + (size_t)p * ENCD);
            float alp = sal[p];
            a0 = fmaf(alp, u.x, a0); a1 = fmaf(alp, u.y, a1);
            a2 = fmaf(alp, u.z, a2); a3 = fmaf(alp, u.w, a3);
        }
    }
    int ei = AA + e0;
    float4 gl = *(const float4*)&battn[ei];
    #pragma unroll
    for (int z = 0; z < NS; ++z) {
        float4 gp = *(const float4*)&pz[z * ps + ei];
        gl.x += gp.x; gl.y += gp.y; gl.z += gp.z; gl.w += gp.w;
    }
    ushort4 xo;
    xo.x = f2bf(a0 * sigmoidf_(gl.x));
    xo.y = f2bf(a1 * sigmoidf_(gl.y));
    xo.z = f2bf(a2 * sigmoidf_(gl.z));
    xo.w = f2bf(a3 * sigmoidf_(gl.w));
    *(ushort4*)&xcat[(size_t)b * XKK + EE + e0] = xo;
}

// ---------------------------------------------------------------------------
// LSTM pointwise for step (t-1): sum NS gate slabs + bias -> h,c update.
// Also fills xcat emb (for step t) and xcat h-slot.
// ---------------------------------------------------------------------------
template<int NS>
__global__ void pointwise_kernel(const float* __restrict__ gates, const float* __restrict__ blstm,
                                 const int* __restrict__ dlen,
                                 const int* __restrict__ si, const int* __restrict__ enc_cap,
                                 const float* __restrict__ emb_W,
                                 float* __restrict__ h, float* __restrict__ c,
                                 unsigned short* __restrict__ h_bf, unsigned short* __restrict__ hstore,
                                 unsigned short* __restrict__ xcat, int t)
{
    int idx = blockIdx.x * 256 + threadIdx.x;
    int b = idx >> 9, d = idx & 511;
    bool act = dlen[b] > (t - 1);
    unsigned short hb;
    if (!act) {
        hstore[((size_t)(t - 1) * B_ + b) * DD + d] = 0;   // fc masks this row anyway
        hb = h_bf[idx];                                     // frozen
    } else {
        const size_t slab = (size_t)B_ * 2048;
        const float* g = gates + (size_t)b * 2048;
        float gi = blstm[d], gf = blstm[512 + d], gg = blstm[1024 + d], go = blstm[1536 + d];
        #pragma unroll
        for (int z = 0; z < NS; ++z) {
            gi += g[z * slab + d];
            gf += g[z * slab + 512 + d];
            gg += g[z * slab + 1024 + d];
            go += g[z * slab + 1536 + d];
        }
        float cn = sigmoidf_(gf) * c[idx] + sigmoidf_(gi) * tanhf(gg);
        float hn = sigmoidf_(go) * tanhf(cn);
        hb = f2bf(hn);
        hstore[((size_t)(t - 1) * B_ + b) * DD + d] = hb;
        h[idx] = hn; c[idx] = cn;
        h_bf[idx] = hb;
    }
    if (t < TT) {
        // fill xcat for step t: emb + h slots (d spans exactly EE)
        int tok = enc_cap[si[b] * LL + t];
        xcat[(size_t)b * XKK + d]        = f2bf(emb_W[(size_t)tok * EE + d]);
        xcat[(size_t)b * XKK + 2560 + d] = hb;
    }
}

// ---------------------------------------------------------------------------
// converts
// ---------------------------------------------------------------------------
__global__ void conv_bf16_kernel(const float* __restrict__ src, unsigned short* __restrict__ dst, int n4)
{
    for (int i = blockIdx.x * 256 + threadIdx.x; i < n4; i += gridDim.x * 256) {
        float4 v = ((const float4*)src)[i];
        ushort4 o;
        o.x = f2bf(v.x); o.y = f2bf(v.y); o.z = f2bf(v.z); o.w = f2bf(v.w);
        ((ushort4*)dst)[i] = o;
    }
}
__global__ void conv_wproj_kernel(const float* __restrict__ dec_W, const float* __restrict__ fbeta_W,
                                  unsigned short* __restrict__ dst)
{   // grid (2, 2560)
    int k = blockIdx.x * 256 + threadIdx.x, n = blockIdx.y;
    float v = (n < AA) ? dec_W[(size_t)n * DD + k] : fbeta_W[(size_t)(n - AA) * DD + k];
    dst[(size_t)n * DD + k] = f2bf(v);
}
__global__ void conv_wcat_kernel(const float* __restrict__ Wih, const float* __restrict__ Whh,
                                 unsigned short* __restrict__ dst)
{   // grid (12, 2048)
    int k = blockIdx.x * 256 + threadIdx.x, n = blockIdx.y;
    float v = (k < 2560) ? Wih[(size_t)n * 2560 + k] : Whh[(size_t)n * DD + (k - 2560)];
    dst[(size_t)n * XKK + k] = f2bf(v);
}
__global__ void conv_fcw_kernel(const float* __restrict__ fc_W, unsigned short* __restrict__ dst)
{   // grid (2, 10048)
    int k = blockIdx.x * 256 + threadIdx.x, n = blockIdx.y;
    float v = (n < VV) ? fc_W[(size_t)n * DD + k] : 0.f;
    dst[(size_t)n * DD + k] = f2bf(v);
}

// ---------------------------------------------------------------------------
extern "C" void kernel_launch(void* const* d_in, const int* in_sizes, int n_in,
                              void* d_out, int out_size, void* d_ws, size_t ws_size,
                              hipStream_t stream)
{
    const float* encoder_out = (const float*)d_in[0];
    const int*   enc_cap     = (const int*)d_in[1];
    const int*   cap_len     = (const int*)d_in[2];
    const float* emb_W       = (const float*)d_in[3];
    const float* init_h_W    = (const float*)d_in[4];
    const float* init_h_b    = (const float*)d_in[5];
    const float* init_c_W    = (const float*)d_in[6];
    const float* init_c_b    = (const float*)d_in[7];
    const float* enc_attn_W  = (const float*)d_in[8];
    const float* enc_attn_b  = (const float*)d_in[9];
    const float* dec_attn_W  = (const float*)d_in[10];
    const float* dec_attn_b  = (const float*)d_in[11];
    const float* full_attn_W = (const float*)d_in[12];
    const float* full_attn_b = (const float*)d_in[13];
    const float* lstm_Wih    = (const float*)d_in[14];
    const float* lstm_Whh    = (const float*)d_in[15];
    const float* lstm_bih    = (const float*)d_in[16];
    const float* lstm_bhh    = (const float*)d_in[17];
    const float* fbeta_W     = (const float*)d_in[18];
    const float* fbeta_b     = (const float*)d_in[19];
    const float* fc_W        = (const float*)d_in[20];
    const float* fc_b        = (const float*)d_in[21];

    char* wsb = (char*)d_ws;
    int*   si     = (int*)(wsb + WS_SI);
    int*   dlen   = (int*)(wsb + WS_DLEN);
    float* battn  = (float*)(wsb + WS_BATTN);
    float* blstm  = (float*)(wsb + WS_BLSTM);
    float* means  = (float*)(wsb + WS_MEANS);
    float* h      = (float*)(wsb + WS_H);
    float* c      = (float*)(wsb + WS_C);
    unsigned short* h_bf   = (unsigned short*)(wsb + WS_HBF);
    float* proj   = (float*)(wsb + WS_PROJ);
    unsigned short* xcat   = (unsigned short*)(wsb + WS_XCAT);
    float* gates  = (float*)(wsb + WS_GATES);
    unsigned short* hstore = (unsigned short*)(wsb + WS_HSTORE);
    unsigned short* wproj  = (unsigned short*)(wsb + WS_WPROJ);
    unsigned short* wcat   = (unsigned short*)(wsb + WS_WCAT);
    unsigned short* fcw    = (unsigned short*)(wsb + WS_FCW);
    unsigned short* wenc   = (unsigned short*)(wsb + WS_WENC);
    unsigned short* efeat  = (unsigned short*)(wsb + WS_EFEAT);
    unsigned short* encbf  = (unsigned short*)(wsb + WS_ENCBF);

    float* out      = (float*)d_out;
    float* out0     = out + OUT0_OFF;
    float* out_caps = out + OUT1_OFF;
    float* out_dlen = out + OUT2_OFF;
    float* alphas   = out + OUT3_OFF;
    float* out_sind = out + OUT4_OFF;

    const int use_encbf = (ws_size >= NEED_ENCBF) ? 1 : 0;

    // ---- setup ----
    sort_kernel<<<1, B_, 0, stream>>>(cap_len, enc_cap, si, dlen, out_caps, out_dlen, out_sind);
    bias_cat_kernel<<<10, 256, 0, stream>>>(dec_attn_b, fbeta_b, lstm_bih, lstm_bhh, battn, blstm);
    enc_mean_sorted<<<(B_ * ENCD) / 256, 256, 0, stream>>>(encoder_out, si, means);

    mfma_gemm<0, true, 32><<<dim3(DD / 64, 1, 1), 256, 0, stream>>>(
        means, init_h_W, init_h_b, nullptr, h, nullptr, ENCD, ENCD, DD, 0, DD);
    mfma_gemm<0, true, 32><<<dim3(DD / 64, 1, 1), 256, 0, stream>>>(
        means, init_c_W, init_c_b, nullptr, c, nullptr, ENCD, ENCD, DD, 0, DD);
    conv_bf16_kernel<<<64, 256, 0, stream>>>(h, h_bf, (B_ * DD) / 4);

    conv_wproj_kernel<<<dim3(2, PROJN), 256, 0, stream>>>(dec_attn_W, fbeta_W, wproj);
    conv_wcat_kernel<<<dim3(12, 2048), 256, 0, stream>>>(lstm_Wih, lstm_Whh, wcat);
    conv_fcw_kernel<<<dim3(2, VPAD), 256, 0, stream>>>(fc_W, fcw);
    conv_bf16_kernel<<<256, 256, 0, stream>>>(enc_attn_W, wenc, (AA * ENCD) / 4);
    if (use_encbf)
        conv_bf16_kernel<<<2048, 256, 0, stream>>>(encoder_out, encbf, (B_ * P_ * ENCD) / 4);

    if (use_encbf)
        mfma_gemm<1, false, 64><<<dim3(AA / 64, (B_ * P_) / 128, 1), 256, 0, stream>>>(
            encbf, wenc, enc_attn_b, nullptr, nullptr, efeat, ENCD, ENCD, AA, 0, AA);
    else
        mfma_gemm<1, true, 32><<<dim3(AA / 64, (B_ * P_) / 128, 1), 256, 0, stream>>>(
            encoder_out, enc_attn_W, enc_attn_b, nullptr, nullptr, efeat, ENCD, ENCD, AA, 0, AA);

    // ---- decode loop: 4 dispatches/step ----
    for (int t = 0; t < TT; ++t) {
        if (t > 0)
            pointwise_kernel<8><<<(B_ * DD) / 256, 256, 0, stream>>>(
                gates, blstm, dlen, si, enc_cap, emb_W, h, c, h_bf, hstore, xcat, t);

        // proj = h_bf @ [dec_attn|fbeta]^T : split-K x4 slabs (bias in consumers)
        mfma_gemm<0, false, 64><<<dim3(PROJN / 64, 1, 4), 256, 0, stream>>>(
            h_bf, wproj, nullptr, nullptr, proj, nullptr, DD, 128, PROJN, (long long)B_ * PROJN, PROJN);

        attn_kernel<4><<<dim3(2, B_), 256, 0, stream>>>(
            efeat, proj, battn, full_attn_W, full_attn_b, si, dlen, enc_cap, emb_W, h_bf,
            encbf, encoder_out, use_encbf, alphas, xcat, t);

        // gates = x_cat @ [Wih|Whh]^T : split-K x8 slabs (bias in pointwise)
        mfma_gemm<0, false, 64><<<dim3(2048 / 64, 1, 8), 256, 0, stream>>>(
            xcat, wcat, nullptr, nullptr, gates, nullptr, XKK, 384, 2048, (long long)B_ * 2048, 2048);
    }
    pointwise_kernel<8><<<(B_ * DD) / 256, 256, 0, stream>>>(
        gates, blstm, dlen, si, enc_cap, emb_W, h, c, h_bf, hstore, xcat, TT);

    // fc over all steps: XCD 2D-region swizzled 1D grid (8 x 1000 blocks)
    mfma_gemm<2, false, 64><<<dim3(8000), 256, 0, stream>>>(
        hstore, fcw, fc_b, dlen, out0, nullptr, DD, DD, VV, 0, VV);
}